// Round 1
// baseline (1353.676 us; speedup 1.0000x reference)
//
#include <hip/hip_runtime.h>
#include <cstdint>
#include <cstddef>

#define NB 1024
#define NN 64
#define NF 64
#define NE 16
#define NM 128
#define NO 128

// ws layout (floats): W_nu [64*64] | W_eu [16*64] | b_mu [64]
#define WNU_OFF 0
#define WEU_OFF (64 * 64)
#define BMU_OFF (64 * 64 + 16 * 64)

// ---------------------------------------------------------------------------
// prep: fold W_n/W_e/b_m through W_u2 (rows 64..191 of W_u) once per launch.
//   W_nu = W_n @ W_u2   [64][64]
//   W_eu = W_e @ W_u2   [16][64]
//   b_mu = b_m @ W_u2 + b_u   [64]
// ---------------------------------------------------------------------------
__global__ __launch_bounds__(256) void prep_kernel(
    const float* __restrict__ W_n, const float* __restrict__ W_e,
    const float* __restrict__ b_m, const float* __restrict__ W_u,
    const float* __restrict__ b_u, float* __restrict__ ws)
{
    const int t = threadIdx.x;
    const float* Wu2 = W_u + 64 * NF;  // [128][64] row-major

    // W_nu: 4096 outputs, 16 per thread
    {
        const int i = t >> 2, jb = (t & 3) * 16;
        float acc[16];
#pragma unroll
        for (int j = 0; j < 16; ++j) acc[j] = 0.f;
        for (int k = 0; k < 128; ++k) {
            const float a = W_n[i * 128 + k];
            const float* w = Wu2 + k * 64 + jb;
#pragma unroll
            for (int j = 0; j < 16; ++j) acc[j] += a * w[j];
        }
        for (int j = 0; j < 16; ++j) ws[WNU_OFF + i * 64 + jb + j] = acc[j];
    }
    // W_eu: 1024 outputs, 4 per thread
    {
        const int e = t >> 4, jb = (t & 15) * 4;
        float acc[4] = {0.f, 0.f, 0.f, 0.f};
        for (int k = 0; k < 128; ++k) {
            const float a = W_e[e * 128 + k];
            const float* w = Wu2 + k * 64 + jb;
#pragma unroll
            for (int j = 0; j < 4; ++j) acc[j] += a * w[j];
        }
        for (int j = 0; j < 4; ++j) ws[WEU_OFF + e * 64 + jb + j] = acc[j];
    }
    if (t < 64) {
        float acc = b_u[t];
        for (int k = 0; k < 128; ++k) acc += b_m[k] * Wu2[k * 64 + t];
        ws[BMU_OFF + t] = acc;
    }
}

// ---------------------------------------------------------------------------
// main: one block per graph. thread t -> (v = t>>2, l4 = t&3); thread owns
// 16-col strip [l4*16, l4*16+16) for F-sized outputs, 32-col strip for O=128.
// ---------------------------------------------------------------------------
__global__ __launch_bounds__(256) void mpnn_kernel(
    const int* __restrict__ adjacency, const float* __restrict__ nodes,
    const float* __restrict__ edges, const float* __restrict__ W_u,
    const float* __restrict__ W_r, const float* __restrict__ b_r,
    const float* __restrict__ ws, float* __restrict__ out)
{
    // stride 68 = 64+4 pad: column reads hit 8 distinct banks (2-way, free)
    // instead of stride-64's 16-way conflict; 272B row stride keeps 16B align.
    __shared__ __align__(16) float h[64][68];
    __shared__ __align__(16) float aggh[64][68];   // reused for nodes at readout
    __shared__ __align__(16) float msgc[64][68];
    __shared__ __align__(16) float agge[64][20];   // also mask-build scratch
    __shared__ unsigned long long maskRow[64];
    __shared__ __align__(16) float partial[4][128];

    const int b = blockIdx.x;
    const int t = threadIdx.x;
    const int v = t >> 2;
    const int l4 = t & 3;
    const int cb = l4 * 16;

    // ---- adjacency -> per-row 64-bit masks (16-bit chunk per thread) ----
    {
        const int* arow = adjacency + (b * NN + v) * NN + l4 * 16;
        unsigned m16 = 0;
#pragma unroll
        for (int i = 0; i < 16; ++i) m16 |= (arow[i] != 0) ? (1u << i) : 0u;
        unsigned* mpart = (unsigned*)&agge[0][0];
        mpart[v * 4 + l4] = m16;
    }
    // ---- stage nodes -> h (independent of mask build) ----
    {
        const float4* np = (const float4*)(nodes + (b * NN + v) * NF + cb);
        float4* hp = (float4*)&h[v][cb];
#pragma unroll
        for (int c = 0; c < 4; ++c) hp[c] = np[c];
    }
    __syncthreads();
    if (t < 64) {
        const unsigned* mpart = (const unsigned*)&agge[0][0];
        maskRow[t] = (unsigned long long)mpart[t * 4 + 0]
                   | ((unsigned long long)mpart[t * 4 + 1] << 16)
                   | ((unsigned long long)mpart[t * 4 + 2] << 32)
                   | ((unsigned long long)mpart[t * 4 + 3] << 48);
    }
    __syncthreads();
    const unsigned long long mrow = maskRow[v];

    // ---- agge[v][:] = sum_{u: adj[v][u]=1} edges[b,v,u,:]  (skip saves HBM) ----
    {
        float ax = 0.f, ay = 0.f, az = 0.f, aw = 0.f;
        const float* ebase = edges + (size_t)(b * NN + v) * (NN * NE) + l4 * 4;
        for (int u = 0; u < 64; ++u) {
            if ((mrow >> u) & 1ULL) {  // uniform within the 4-lane group
                const float4 ev = *(const float4*)(ebase + u * NE);
                ax += ev.x; ay += ev.y; az += ev.z; aw += ev.w;
            }
        }
        *(float4*)&agge[v][l4 * 4] = make_float4(ax, ay, az, aw);
    }
    // ---- msgc[v][:] = agge[v] @ W_eu + b_mu  (agge row v is wave-local) ----
    {
        float acc[16];
        const float* bmu = ws + BMU_OFF + cb;
#pragma unroll
        for (int c = 0; c < 16; ++c) acc[c] = bmu[c];
#pragma unroll
        for (int e = 0; e < 16; ++e) {
            const float a = agge[v][e];
            const float* w = ws + WEU_OFF + e * 64 + cb;
#pragma unroll
            for (int c = 0; c < 16; ++c) acc[c] += a * w[c];
        }
        for (int c = 0; c < 16; ++c) msgc[v][cb + c] = acc[c];
    }

    const float* Wu1 = W_u;            // rows 0..63 (h part of concat)
    const float* Wnu = ws + WNU_OFF;

    for (int pass = 0; pass < 4; ++pass) {
        // step 1: aggh[v][strip] = sum of neighbour h rows (adj is 0/1 -> adds)
        float s[16];
#pragma unroll
        for (int c = 0; c < 16; ++c) s[c] = 0.f;
        for (int u = 0; u < 64; ++u) {
            if ((mrow >> u) & 1ULL) {
                const float4* hp = (const float4*)&h[u][cb];
#pragma unroll
                for (int c = 0; c < 4; ++c) {
                    const float4 hv = hp[c];
                    s[4 * c + 0] += hv.x; s[4 * c + 1] += hv.y;
                    s[4 * c + 2] += hv.z; s[4 * c + 3] += hv.w;
                }
            }
        }
        {
            float4* ap = (float4*)&aggh[v][cb];
#pragma unroll
            for (int c = 0; c < 4; ++c)
                ap[c] = make_float4(s[4 * c], s[4 * c + 1], s[4 * c + 2], s[4 * c + 3]);
        }
        __syncthreads();  // all waves finished reading old h

        // step 2: h_new = relu(h@Wu1 + aggh@Wnu + msgc); rows are wave-local
        float acc[16];
#pragma unroll
        for (int c = 0; c < 16; ++c) acc[c] = msgc[v][cb + c];
        for (int k = 0; k < 64; ++k) {
            const float ah = h[v][k];
            const float ag = aggh[v][k];
            const float4* w1 = (const float4*)(Wu1 + k * 64 + cb);
            const float4* w2 = (const float4*)(Wnu + k * 64 + cb);
#pragma unroll
            for (int c = 0; c < 4; ++c) {
                const float4 w1v = w1[c], w2v = w2[c];
                acc[4 * c + 0] += ah * w1v.x + ag * w2v.x;
                acc[4 * c + 1] += ah * w1v.y + ag * w2v.y;
                acc[4 * c + 2] += ah * w1v.z + ag * w2v.z;
                acc[4 * c + 3] += ah * w1v.w + ag * w2v.w;
            }
        }
        if (mrow != 0ULL) {  // node_mask: only update nodes with degree > 0
#pragma unroll
            for (int c = 0; c < 16; ++c) h[v][cb + c] = fmaxf(acc[c], 0.f);
        }
        __syncthreads();  // h writes visible before next pass
    }

    // ---- readout: r = relu(h@Wr1 + nodes@Wr2 + b_r); out = masked node-sum ----
    {
        const float4* np = (const float4*)(nodes + (b * NN + v) * NF + cb);
        float4* gp = (float4*)&aggh[v][cb];   // reuse aggh for original nodes
#pragma unroll
        for (int c = 0; c < 4; ++c) gp[c] = np[c];
    }
    __syncthreads();

    const int ob = l4 * 32;
    float acc[32];
    {
        const float* br = b_r + ob;
#pragma unroll
        for (int j = 0; j < 32; ++j) acc[j] = br[j];
    }
    for (int k = 0; k < 64; ++k) {
        const float a = h[v][k];
        const float4* wr = (const float4*)(W_r + k * NO + ob);
#pragma unroll
        for (int c = 0; c < 8; ++c) {
            const float4 w = wr[c];
            acc[4 * c + 0] += a * w.x; acc[4 * c + 1] += a * w.y;
            acc[4 * c + 2] += a * w.z; acc[4 * c + 3] += a * w.w;
        }
    }
    for (int k = 0; k < 64; ++k) {
        const float a = aggh[v][k];  // original nodes
        const float4* wr = (const float4*)(W_r + (64 + k) * NO + ob);
#pragma unroll
        for (int c = 0; c < 8; ++c) {
            const float4 w = wr[c];
            acc[4 * c + 0] += a * w.x; acc[4 * c + 1] += a * w.y;
            acc[4 * c + 2] += a * w.z; acc[4 * c + 3] += a * w.w;
        }
    }
    const float mval = (mrow != 0ULL) ? 1.f : 0.f;
#pragma unroll
    for (int j = 0; j < 32; ++j) acc[j] = fmaxf(acc[j], 0.f) * mval;

    // reduce over the 16 v-rows held within each wave (lanes sharing l4)
#pragma unroll
    for (int off = 4; off < 64; off <<= 1) {
#pragma unroll
        for (int j = 0; j < 32; ++j) acc[j] += __shfl_xor(acc[j], off, 64);
    }
    const int lane = t & 63, wv = t >> 6;
    if (lane < 4) {
#pragma unroll
        for (int j = 0; j < 32; ++j) partial[wv][lane * 32 + j] = acc[j];
    }
    __syncthreads();
    if (t < 128) {
        out[b * NO + t] = partial[0][t] + partial[1][t] + partial[2][t] + partial[3][t];
    }
}

// ---------------------------------------------------------------------------
extern "C" void kernel_launch(void* const* d_in, const int* in_sizes, int n_in,
                              void* d_out, int out_size, void* d_ws, size_t ws_size,
                              hipStream_t stream)
{
    const int*   adjacency = (const int*)  d_in[0];
    const float* nodes     = (const float*)d_in[1];
    const float* edges     = (const float*)d_in[2];
    const float* W_n       = (const float*)d_in[3];
    const float* W_e       = (const float*)d_in[4];
    const float* b_m       = (const float*)d_in[5];
    const float* W_u       = (const float*)d_in[6];
    const float* b_u       = (const float*)d_in[7];
    const float* W_r       = (const float*)d_in[8];
    const float* b_r       = (const float*)d_in[9];
    float* out = (float*)d_out;
    float* ws  = (float*)d_ws;   // needs 5184 floats (~21 KB)

    prep_kernel<<<1, 256, 0, stream>>>(W_n, W_e, b_m, W_u, b_u, ws);
    mpnn_kernel<<<NB, 256, 0, stream>>>(adjacency, nodes, edges, W_u, W_r, b_r, ws, out);
}

// Round 5
// 548.012 us; speedup vs baseline: 2.4702x; 2.4702x over previous
//
#include <hip/hip_runtime.h>
#include <cstdint>
#include <cstddef>

// native clang vectors: required by __builtin_nontemporal_load
typedef float f32x4 __attribute__((ext_vector_type(4)));
typedef int   i32x4 __attribute__((ext_vector_type(4)));

// ws layout (floats): W_nu [64*64] | W_eu [16*64] | b_mu [64]
#define WNU_OFF 0
#define WEU_OFF (64 * 64)
#define BMU_OFF (64 * 64 + 16 * 64)

// ---------------------------------------------------------------------------
// prep: fold W_n/W_e/b_m through W_u2 (rows 64..191 of W_u).
// 81 blocks x 64 threads: blocks 0..63 -> W_nu rows, 64..79 -> W_eu rows,
// 80 -> b_mu. Each block: k-loop with uniform (SALU) a-operand, coalesced Wu2.
// ---------------------------------------------------------------------------
__global__ __launch_bounds__(64) void prep_kernel(
    const float* __restrict__ W_n, const float* __restrict__ W_e,
    const float* __restrict__ b_m, const float* __restrict__ W_u,
    const float* __restrict__ b_u, float* __restrict__ ws)
{
    const int blk = blockIdx.x, j = threadIdx.x;
    const float* Wu2 = W_u + 64 * 64;  // [128][64] row-major
    if (blk < 64) {
        float acc = 0.f;
        for (int k = 0; k < 128; ++k) acc += W_n[blk * 128 + k] * Wu2[k * 64 + j];
        ws[WNU_OFF + blk * 64 + j] = acc;
    } else if (blk < 80) {
        const int e = blk - 64;
        float acc = 0.f;
        for (int k = 0; k < 128; ++k) acc += W_e[e * 128 + k] * Wu2[k * 64 + j];
        ws[WEU_OFF + e * 64 + j] = acc;
    } else {
        float acc = b_u[j];
        for (int k = 0; k < 128; ++k) acc += b_m[k] * Wu2[k * 64 + j];
        ws[BMU_OFF + j] = acc;
    }
}

// ---------------------------------------------------------------------------
// main: one block (256 thr) per graph.
// Thread tile: rows {rg, rg+16, rg+32, rg+48} (rg = t>>4, same-wave per row)
// x cols 4*cg..4*cg+3 (cg = t&15).  h/agg ping-pong between bufA/bufB with
// ONE barrier per pass (cross-wave reads only touch the read-only cur buffer).
// ---------------------------------------------------------------------------
__global__ __launch_bounds__(256, 3) void mpnn_kernel(
    const int* __restrict__ adjacency, const float* __restrict__ nodes,
    const float* __restrict__ edges, const float* __restrict__ W_u,
    const float* __restrict__ W_r, const float* __restrict__ b_r,
    const float* __restrict__ ws, float* __restrict__ out)
{
    // stride 68 pad: column (fixed-k) reads spread banks; rows 16 apart alias
    // only 2-4 ways (free-cheap per m136).
    __shared__ __align__(16) float bufA[64 * 68];
    __shared__ __align__(16) float bufB[64 * 68];
    __shared__ unsigned long long maskRow[64];
    __shared__ __align__(16) float scratch[16 * 128];  // mask-parts | agge[64][20] | red[16][128]

    const int b  = blockIdx.x;
    const int t  = threadIdx.x;
    const int w  = t >> 6;       // wave 0..3
    const int l  = t & 63;       // lane
    const int rg = t >> 4;       // row group 0..15
    const int cg = t & 15;       // col group 0..15

    // ---- adjacency -> 16-bit mask chunks (coalesced int4, nontemporal) ----
    {
        const i32x4* arow = (const i32x4*)(adjacency + ((size_t)b * 64 + (t >> 2)) * 64 + (t & 3) * 16);
        unsigned m16 = 0;
#pragma unroll
        for (int j = 0; j < 4; ++j) {
            const i32x4 a = __builtin_nontemporal_load(arow + j);
            m16 |= (a.x != 0 ? 1u : 0u) << (4 * j + 0);
            m16 |= (a.y != 0 ? 1u : 0u) << (4 * j + 1);
            m16 |= (a.z != 0 ? 1u : 0u) << (4 * j + 2);
            m16 |= (a.w != 0 ? 1u : 0u) << (4 * j + 3);
        }
        ((unsigned*)scratch)[t] = m16;
    }
    // ---- stage nodes -> bufA (coalesced) ----
    {
        const int v = t >> 2, cb = (t & 3) * 16;
        const float4* np = (const float4*)(nodes + ((size_t)b * 64 + v) * 64 + cb);
        float4* hp = (float4*)&bufA[v * 68 + cb];
#pragma unroll
        for (int cc = 0; cc < 4; ++cc) hp[cc] = np[cc];
    }
    __syncthreads();
    if (t < 64) {
        const unsigned* mp = (const unsigned*)scratch;
        maskRow[t] = (unsigned long long)mp[t * 4 + 0]
                   | ((unsigned long long)mp[t * 4 + 1] << 16)
                   | ((unsigned long long)mp[t * 4 + 2] << 32)
                   | ((unsigned long long)mp[t * 4 + 3] << 48);
    }
    __syncthreads();

    // ---- edge aggregation: unconditional coalesced stream, mask-multiply ----
    // lane = (vs, us, e4); wave w covers rows 16w..16w+15 (4 groups of 4).
    // Per instr: 4 contiguous 256B segments. Reduce over us via 2 xor-shuffles.
    {
        const int vs = l >> 4, us = (l >> 2) & 3, e4 = l & 3;
        float* agge = scratch;  // [64][20]
#pragma unroll
        for (int g = 0; g < 4; ++g) {
            const int v = 16 * w + 4 * g + vs;
            const unsigned long long mv = maskRow[v];
            const unsigned mlo = (unsigned)mv, mhi = (unsigned)(mv >> 32);
            const float* ebase = edges + ((size_t)b * 64 + v) * 1024 + us * 16 + e4 * 4;
            float a0 = 0.f, a1 = 0.f, a2 = 0.f, a3 = 0.f;
#pragma unroll
            for (int i = 0; i < 16; ++i) {
                const unsigned mm = (i < 8) ? mlo : mhi;           // compile-time select
                const float m = (float)((mm >> ((i * 4) & 31)) >> us & 1u);
                const f32x4 ev = __builtin_nontemporal_load((const f32x4*)(ebase + i * 64));
                a0 += m * ev.x; a1 += m * ev.y; a2 += m * ev.z; a3 += m * ev.w;
            }
#pragma unroll
            for (int off = 4; off <= 8; off <<= 1) {
                a0 += __shfl_xor(a0, off, 64);
                a1 += __shfl_xor(a1, off, 64);
                a2 += __shfl_xor(a2, off, 64);
                a3 += __shfl_xor(a3, off, 64);
            }
            if (us == 0) *(float4*)&agge[v * 20 + e4 * 4] = make_float4(a0, a1, a2, a3);
        }
    }
    __syncthreads();

    // ---- own-row masks ----
    unsigned long long mk[4];
    float updf[4];
#pragma unroll
    for (int i = 0; i < 4; ++i) {
        mk[i] = maskRow[rg + 16 * i];
        updf[i] = (mk[i] != 0ULL) ? 1.f : 0.f;
    }

    // ---- msg (pass-invariant edge term) kept in registers: 4 rows x 4 cols ----
    float msg[4][4];
    {
        const float* Weu = ws + WEU_OFF;
        const float* agge = scratch;
        const float4 bm = *(const float4*)(ws + BMU_OFF + 4 * cg);
#pragma unroll
        for (int i = 0; i < 4; ++i) {
            const int v = rg + 16 * i;
            float m0 = bm.x, m1 = bm.y, m2 = bm.z, m3 = bm.w;
#pragma unroll
            for (int e = 0; e < 16; ++e) {
                const float a = agge[v * 20 + e];
                const float4 wv = *(const float4*)(Weu + e * 64 + 4 * cg);
                m0 += a * wv.x; m1 += a * wv.y; m2 += a * wv.z; m3 += a * wv.w;
            }
            msg[i][0] = m0; msg[i][1] = m1; msg[i][2] = m2; msg[i][3] = m3;
        }
    }
    __syncthreads();  // agge fully consumed; scratch reusable later

    const float* Wu1 = W_u;            // rows 0..63 of W_u (h part of concat)
    const float* Wnu = ws + WNU_OFF;
    float* cur = bufA;
    float* oth = bufB;

    for (int pass = 0; pass < 4; ++pass) {
        // step 1: agg[own rows][4 cols] = sum_u mask(v,u) * h[u][4 cols]
        float s[4][4];
#pragma unroll
        for (int i = 0; i < 4; ++i)
#pragma unroll
            for (int j = 0; j < 4; ++j) s[i][j] = 0.f;
#pragma unroll 1
        for (int half = 0; half < 2; ++half) {
            unsigned mm0 = (unsigned)(mk[0] >> (32 * half));
            unsigned mm1 = (unsigned)(mk[1] >> (32 * half));
            unsigned mm2 = (unsigned)(mk[2] >> (32 * half));
            unsigned mm3 = (unsigned)(mk[3] >> (32 * half));
            const float* hb = cur + (half * 32) * 68 + 4 * cg;
#pragma unroll 8
            for (int uu = 0; uu < 32; ++uu) {
                const float4 hv = *(const float4*)(hb + uu * 68);
                const float f0 = (float)(mm0 & 1u); mm0 >>= 1;
                const float f1 = (float)(mm1 & 1u); mm1 >>= 1;
                const float f2 = (float)(mm2 & 1u); mm2 >>= 1;
                const float f3 = (float)(mm3 & 1u); mm3 >>= 1;
                s[0][0] += f0 * hv.x; s[0][1] += f0 * hv.y; s[0][2] += f0 * hv.z; s[0][3] += f0 * hv.w;
                s[1][0] += f1 * hv.x; s[1][1] += f1 * hv.y; s[1][2] += f1 * hv.z; s[1][3] += f1 * hv.w;
                s[2][0] += f2 * hv.x; s[2][1] += f2 * hv.y; s[2][2] += f2 * hv.z; s[2][3] += f2 * hv.w;
                s[3][0] += f3 * hv.x; s[3][1] += f3 * hv.y; s[3][2] += f3 * hv.z; s[3][3] += f3 * hv.w;
            }
        }
#pragma unroll
        for (int i = 0; i < 4; ++i)
            *(float4*)&oth[(rg + 16 * i) * 68 + 4 * cg] =
                make_float4(s[i][0], s[i][1], s[i][2], s[i][3]);
        // no barrier: oth rows are own-wave only; cur is read-only this pass

        // step 2: h_new = relu(h@Wu1 + agg@Wnu + msg)
        float acc[4][4];
#pragma unroll
        for (int i = 0; i < 4; ++i)
#pragma unroll
            for (int j = 0; j < 4; ++j) acc[i][j] = msg[i][j];
#pragma unroll 8
        for (int k = 0; k < 64; ++k) {
            const float4 w1 = *(const float4*)(Wu1 + k * 64 + 4 * cg);
            const float4 w2 = *(const float4*)(Wnu + k * 64 + 4 * cg);
#pragma unroll
            for (int i = 0; i < 4; ++i) {
                const float ah = cur[(rg + 16 * i) * 68 + k];
                const float ag = oth[(rg + 16 * i) * 68 + k];
                acc[i][0] += ah * w1.x + ag * w2.x;
                acc[i][1] += ah * w1.y + ag * w2.y;
                acc[i][2] += ah * w1.z + ag * w2.z;
                acc[i][3] += ah * w1.w + ag * w2.w;
            }
        }
        // write h_new into oth own rows (after same-wave reads of oth row k's)
#pragma unroll
        for (int i = 0; i < 4; ++i) {
            const int v = rg + 16 * i;
            const float4 oldv = *(const float4*)&cur[v * 68 + 4 * cg];
            float4 nv;
            nv.x = (mk[i] != 0ULL) ? fmaxf(acc[i][0], 0.f) : oldv.x;
            nv.y = (mk[i] != 0ULL) ? fmaxf(acc[i][1], 0.f) : oldv.y;
            nv.z = (mk[i] != 0ULL) ? fmaxf(acc[i][2], 0.f) : oldv.z;
            nv.w = (mk[i] != 0ULL) ? fmaxf(acc[i][3], 0.f) : oldv.w;
            *(float4*)&oth[v * 68 + 4 * cg] = nv;
        }
        __syncthreads();  // one barrier per pass; then swap roles
        float* tmp = cur; cur = oth; oth = tmp;
    }
    // after 4 passes: cur == bufA holds final h; oth == bufB is free

    // ---- stage original nodes into oth (own rows -> no barrier needed) ----
#pragma unroll
    for (int i = 0; i < 4; ++i) {
        const int v = rg + 16 * i;
        const float4 nv = *(const float4*)(nodes + ((size_t)b * 64 + v) * 64 + 4 * cg);
        *(float4*)&oth[v * 68 + 4 * cg] = nv;
    }

    // ---- readout: r = relu([h, nodes] @ W_r + b_r), masked row-sum ----
    float ro[4][8];
    {
        const float4 br0 = *(const float4*)(b_r + 8 * cg);
        const float4 br1 = *(const float4*)(b_r + 8 * cg + 4);
#pragma unroll
        for (int i = 0; i < 4; ++i) {
            ro[i][0] = br0.x; ro[i][1] = br0.y; ro[i][2] = br0.z; ro[i][3] = br0.w;
            ro[i][4] = br1.x; ro[i][5] = br1.y; ro[i][6] = br1.z; ro[i][7] = br1.w;
        }
    }
#pragma unroll 4
    for (int k = 0; k < 64; ++k) {
        const float4 wa = *(const float4*)(W_r + k * 128 + 8 * cg);
        const float4 wb = *(const float4*)(W_r + k * 128 + 8 * cg + 4);
#pragma unroll
        for (int i = 0; i < 4; ++i) {
            const float ah = cur[(rg + 16 * i) * 68 + k];
            ro[i][0] += ah * wa.x; ro[i][1] += ah * wa.y; ro[i][2] += ah * wa.z; ro[i][3] += ah * wa.w;
            ro[i][4] += ah * wb.x; ro[i][5] += ah * wb.y; ro[i][6] += ah * wb.z; ro[i][7] += ah * wb.w;
        }
    }
#pragma unroll 4
    for (int k = 0; k < 64; ++k) {
        const float4 wa = *(const float4*)(W_r + (64 + k) * 128 + 8 * cg);
        const float4 wb = *(const float4*)(W_r + (64 + k) * 128 + 8 * cg + 4);
#pragma unroll
        for (int i = 0; i < 4; ++i) {
            const float an = oth[(rg + 16 * i) * 68 + k];
            ro[i][0] += an * wa.x; ro[i][1] += an * wa.y; ro[i][2] += an * wa.z; ro[i][3] += an * wa.w;
            ro[i][4] += an * wb.x; ro[i][5] += an * wb.y; ro[i][6] += an * wb.z; ro[i][7] += an * wb.w;
        }
    }
    // relu + node mask + in-thread row sum
    float rs[8];
#pragma unroll
    for (int j = 0; j < 8; ++j) rs[j] = 0.f;
#pragma unroll
    for (int i = 0; i < 4; ++i)
#pragma unroll
        for (int j = 0; j < 8; ++j) rs[j] += updf[i] * fmaxf(ro[i][j], 0.f);

    float* red = scratch;  // [16][128]
    *(float4*)&red[rg * 128 + 8 * cg]     = make_float4(rs[0], rs[1], rs[2], rs[3]);
    *(float4*)&red[rg * 128 + 8 * cg + 4] = make_float4(rs[4], rs[5], rs[6], rs[7]);
    __syncthreads();
    if (t < 128) {
        float sum = 0.f;
#pragma unroll
        for (int i = 0; i < 16; ++i) sum += red[i * 128 + t];
        out[(size_t)b * 128 + t] = sum;
    }
}

// ---------------------------------------------------------------------------
extern "C" void kernel_launch(void* const* d_in, const int* in_sizes, int n_in,
                              void* d_out, int out_size, void* d_ws, size_t ws_size,
                              hipStream_t stream)
{
    const int*   adjacency = (const int*)  d_in[0];
    const float* nodes     = (const float*)d_in[1];
    const float* edges     = (const float*)d_in[2];
    const float* W_n       = (const float*)d_in[3];
    const float* W_e       = (const float*)d_in[4];
    const float* b_m       = (const float*)d_in[5];
    const float* W_u       = (const float*)d_in[6];
    const float* b_u       = (const float*)d_in[7];
    const float* W_r       = (const float*)d_in[8];
    const float* b_r       = (const float*)d_in[9];
    float* out = (float*)d_out;
    float* ws  = (float*)d_ws;   // 5184 floats

    prep_kernel<<<81, 64, 0, stream>>>(W_n, W_e, b_m, W_u, b_u, ws);
    mpnn_kernel<<<1024, 256, 0, stream>>>(adjacency, nodes, edges, W_u, W_r, b_r, ws, out);
}

// Round 6
// 511.144 us; speedup vs baseline: 2.6483x; 1.0721x over previous
//
#include <hip/hip_runtime.h>
#include <cstdint>
#include <cstddef>

// native clang vectors: required by __builtin_nontemporal_load + [] indexing
typedef float f32x4 __attribute__((ext_vector_type(4)));
typedef int   i32x4 __attribute__((ext_vector_type(4)));

// ws layout (floats): W_nu [64*64] | W_eu [16*64] | b_mu [64]
#define WNU_OFF 0
#define WEU_OFF (64 * 64)
#define BMU_OFF (64 * 64 + 16 * 64)

// ---------------------------------------------------------------------------
// prep: fold W_n/W_e/b_m through W_u2 (rows 64..191 of W_u).
// ---------------------------------------------------------------------------
__global__ __launch_bounds__(64) void prep_kernel(
    const float* __restrict__ W_n, const float* __restrict__ W_e,
    const float* __restrict__ b_m, const float* __restrict__ W_u,
    const float* __restrict__ b_u, float* __restrict__ ws)
{
    const int blk = blockIdx.x, j = threadIdx.x;
    const float* Wu2 = W_u + 64 * 64;  // [128][64] row-major
    if (blk < 64) {
        float acc = 0.f;
        for (int k = 0; k < 128; ++k) acc += W_n[blk * 128 + k] * Wu2[k * 64 + j];
        ws[WNU_OFF + blk * 64 + j] = acc;
    } else if (blk < 80) {
        const int e = blk - 64;
        float acc = 0.f;
        for (int k = 0; k < 128; ++k) acc += W_e[e * 128 + k] * Wu2[k * 64 + j];
        ws[WEU_OFF + e * 64 + j] = acc;
    } else {
        float acc = b_u[j];
        for (int k = 0; k < 128; ++k) acc += b_m[k] * Wu2[k * 64 + j];
        ws[BMU_OFF + j] = acc;
    }
}

// ---------------------------------------------------------------------------
// main: one block (256 thr) per graph. Thread tile: rows {rg,rg+16,rg+32,rg+48}
// x cols 4*cg..4*cg+3. LDS = 2 x [64][68] ping-pong + masks = 34.5 KB -> 4
// blocks/CU. bufB is overlaid with mask-parts -> agge[64][20] -> red[16][128]
// (each overlay separated by the existing barriers).
// ---------------------------------------------------------------------------
__global__ __launch_bounds__(256, 4) void mpnn_kernel(
    const int* __restrict__ adjacency, const float* __restrict__ nodes,
    const float* __restrict__ edges, const float* __restrict__ W_u,
    const float* __restrict__ W_r, const float* __restrict__ b_r,
    const float* __restrict__ ws, float* __restrict__ out)
{
    __shared__ __align__(16) float bufA[64 * 68];
    __shared__ __align__(16) float bufB[64 * 68];
    __shared__ unsigned long long maskRow[64];

    const int b  = blockIdx.x;
    const int t  = threadIdx.x;
    const int w  = t >> 6;       // wave 0..3
    const int l  = t & 63;       // lane
    const int rg = t >> 4;       // row group 0..15
    const int cg = t & 15;       // col group 0..15

    // ---- adjacency -> 16-bit mask chunks (coalesced, nontemporal) ----
    {
        const i32x4* arow = (const i32x4*)(adjacency + ((size_t)b * 64 + (t >> 2)) * 64 + (t & 3) * 16);
        unsigned m16 = 0;
#pragma unroll
        for (int j = 0; j < 4; ++j) {
            const i32x4 a = __builtin_nontemporal_load(arow + j);
            m16 |= (a.x != 0 ? 1u : 0u) << (4 * j + 0);
            m16 |= (a.y != 0 ? 1u : 0u) << (4 * j + 1);
            m16 |= (a.z != 0 ? 1u : 0u) << (4 * j + 2);
            m16 |= (a.w != 0 ? 1u : 0u) << (4 * j + 3);
        }
        ((unsigned*)bufB)[t] = m16;   // overlay 1: mask parts
    }
    // ---- stage nodes -> bufA (coalesced) ----
    {
        const int v = t >> 2, cb = (t & 3) * 16;
        const float4* np = (const float4*)(nodes + ((size_t)b * 64 + v) * 64 + cb);
        float4* hp = (float4*)&bufA[v * 68 + cb];
#pragma unroll
        for (int cc = 0; cc < 4; ++cc) hp[cc] = np[cc];
    }
    __syncthreads();
    if (t < 64) {
        const unsigned* mp = (const unsigned*)bufB;
        maskRow[t] = (unsigned long long)mp[t * 4 + 0]
                   | ((unsigned long long)mp[t * 4 + 1] << 16)
                   | ((unsigned long long)mp[t * 4 + 2] << 32)
                   | ((unsigned long long)mp[t * 4 + 3] << 48);
    }
    __syncthreads();   // mask parts consumed; bufB free for agge

    // ---- edge aggregation: unconditional coalesced stream, mask-multiply ----
    {
        const int vs = l >> 4, us = (l >> 2) & 3, e4 = l & 3;
        float* agge = bufB;  // overlay 2: agge[64][20]
#pragma unroll
        for (int g = 0; g < 4; ++g) {
            const int v = 16 * w + 4 * g + vs;
            const unsigned long long mv = maskRow[v];
            const unsigned mlo = (unsigned)mv, mhi = (unsigned)(mv >> 32);
            const float* ebase = edges + ((size_t)b * 64 + v) * 1024 + us * 16 + e4 * 4;
            float a0 = 0.f, a1 = 0.f, a2 = 0.f, a3 = 0.f;
#pragma unroll
            for (int i = 0; i < 16; ++i) {
                const unsigned mm = (i < 8) ? mlo : mhi;           // compile-time select
                const float m = (float)((mm >> ((i * 4) & 31)) >> us & 1u);
                const f32x4 ev = __builtin_nontemporal_load((const f32x4*)(ebase + i * 64));
                a0 += m * ev.x; a1 += m * ev.y; a2 += m * ev.z; a3 += m * ev.w;
            }
#pragma unroll
            for (int off = 4; off <= 8; off <<= 1) {
                a0 += __shfl_xor(a0, off, 64);
                a1 += __shfl_xor(a1, off, 64);
                a2 += __shfl_xor(a2, off, 64);
                a3 += __shfl_xor(a3, off, 64);
            }
            if (us == 0) *(float4*)&agge[v * 20 + e4 * 4] = make_float4(a0, a1, a2, a3);
        }
    }
    __syncthreads();

    // ---- own-row masks ----
    unsigned long long mk[4];
    float updf[4];
#pragma unroll
    for (int i = 0; i < 4; ++i) {
        mk[i] = maskRow[rg + 16 * i];
        updf[i] = (mk[i] != 0ULL) ? 1.f : 0.f;
    }

    // ---- msg (pass-invariant edge term) in registers: 4 rows x 4 cols ----
    float msg[4][4];
    {
        const float* Weu = ws + WEU_OFF;
        const f32x4 bm = *(const f32x4*)(ws + BMU_OFF + 4 * cg);
#pragma unroll
        for (int i = 0; i < 4; ++i) {
            const int v = rg + 16 * i;
            f32x4 m = bm;
#pragma unroll
            for (int q = 0; q < 4; ++q) {
                const f32x4 a4 = *(const f32x4*)&bufB[v * 20 + q * 4];
#pragma unroll
                for (int qq = 0; qq < 4; ++qq) {
                    const f32x4 wv = *(const f32x4*)(Weu + (q * 4 + qq) * 64 + 4 * cg);
                    m += a4[qq] * wv;
                }
            }
            msg[i][0] = m.x; msg[i][1] = m.y; msg[i][2] = m.z; msg[i][3] = m.w;
        }
    }
    __syncthreads();  // agge consumed; bufB free to become pass-0 'oth'

    const float* Wu1 = W_u;            // rows 0..63 of W_u (h part of concat)
    const float* Wnu = ws + WNU_OFF;
    float* cur = bufA;
    float* oth = bufB;

    for (int pass = 0; pass < 4; ++pass) {
        // step 1: agg[own rows][4 cols] = sum_u mask(v,u) * h[u][4 cols]
        float s[4][4];
#pragma unroll
        for (int i = 0; i < 4; ++i)
#pragma unroll
            for (int j = 0; j < 4; ++j) s[i][j] = 0.f;
#pragma unroll 1
        for (int half = 0; half < 2; ++half) {
            unsigned mm0 = (unsigned)(mk[0] >> (32 * half));
            unsigned mm1 = (unsigned)(mk[1] >> (32 * half));
            unsigned mm2 = (unsigned)(mk[2] >> (32 * half));
            unsigned mm3 = (unsigned)(mk[3] >> (32 * half));
            const float* hb = cur + (half * 32) * 68 + 4 * cg;
#pragma unroll 8
            for (int uu = 0; uu < 32; ++uu) {
                const float4 hv = *(const float4*)(hb + uu * 68);
                const float f0 = (float)(mm0 & 1u); mm0 >>= 1;
                const float f1 = (float)(mm1 & 1u); mm1 >>= 1;
                const float f2 = (float)(mm2 & 1u); mm2 >>= 1;
                const float f3 = (float)(mm3 & 1u); mm3 >>= 1;
                s[0][0] += f0 * hv.x; s[0][1] += f0 * hv.y; s[0][2] += f0 * hv.z; s[0][3] += f0 * hv.w;
                s[1][0] += f1 * hv.x; s[1][1] += f1 * hv.y; s[1][2] += f1 * hv.z; s[1][3] += f1 * hv.w;
                s[2][0] += f2 * hv.x; s[2][1] += f2 * hv.y; s[2][2] += f2 * hv.z; s[2][3] += f2 * hv.w;
                s[3][0] += f3 * hv.x; s[3][1] += f3 * hv.y; s[3][2] += f3 * hv.z; s[3][3] += f3 * hv.w;
            }
        }
#pragma unroll
        for (int i = 0; i < 4; ++i)
            *(float4*)&oth[(rg + 16 * i) * 68 + 4 * cg] =
                make_float4(s[i][0], s[i][1], s[i][2], s[i][3]);
        // no barrier: oth rows are own-wave only; cur is read-only this pass

        // step 2: h_new = relu(h@Wu1 + agg@Wnu + msg); k-vectorized LDS reads
        float acc[4][4];
#pragma unroll
        for (int i = 0; i < 4; ++i)
#pragma unroll
            for (int j = 0; j < 4; ++j) acc[i][j] = msg[i][j];
#pragma unroll 4
        for (int kb = 0; kb < 16; ++kb) {
            f32x4 hq[4], gq[4];
#pragma unroll
            for (int i = 0; i < 4; ++i) {
                hq[i] = *(const f32x4*)&cur[(rg + 16 * i) * 68 + 4 * kb];
                gq[i] = *(const f32x4*)&oth[(rg + 16 * i) * 68 + 4 * kb];
            }
#pragma unroll
            for (int kk = 0; kk < 4; ++kk) {
                const f32x4 w1 = *(const f32x4*)(Wu1 + (4 * kb + kk) * 64 + 4 * cg);
                const f32x4 w2 = *(const f32x4*)(Wnu + (4 * kb + kk) * 64 + 4 * cg);
#pragma unroll
                for (int i = 0; i < 4; ++i) {
                    acc[i][0] += hq[i][kk] * w1.x + gq[i][kk] * w2.x;
                    acc[i][1] += hq[i][kk] * w1.y + gq[i][kk] * w2.y;
                    acc[i][2] += hq[i][kk] * w1.z + gq[i][kk] * w2.z;
                    acc[i][3] += hq[i][kk] * w1.w + gq[i][kk] * w2.w;
                }
            }
        }
        // write h_new into oth own rows
#pragma unroll
        for (int i = 0; i < 4; ++i) {
            const int v = rg + 16 * i;
            const float4 oldv = *(const float4*)&cur[v * 68 + 4 * cg];
            float4 nv;
            nv.x = (mk[i] != 0ULL) ? fmaxf(acc[i][0], 0.f) : oldv.x;
            nv.y = (mk[i] != 0ULL) ? fmaxf(acc[i][1], 0.f) : oldv.y;
            nv.z = (mk[i] != 0ULL) ? fmaxf(acc[i][2], 0.f) : oldv.z;
            nv.w = (mk[i] != 0ULL) ? fmaxf(acc[i][3], 0.f) : oldv.w;
            *(float4*)&oth[v * 68 + 4 * cg] = nv;
        }
        __syncthreads();  // one barrier per pass; then swap roles
        float* tmp = cur; cur = oth; oth = tmp;
    }
    // after 4 passes: cur == bufA holds final h; oth == bufB free

    // ---- stage original nodes into oth (own rows; same-wave use only) ----
#pragma unroll
    for (int i = 0; i < 4; ++i) {
        const int v = rg + 16 * i;
        const float4 nv = *(const float4*)(nodes + ((size_t)b * 64 + v) * 64 + 4 * cg);
        *(float4*)&oth[v * 68 + 4 * cg] = nv;
    }

    // ---- readout: r = relu([h, nodes] @ W_r + b_r), masked row-sum ----
    float ro[4][8];
    {
        const f32x4 br0 = *(const f32x4*)(b_r + 8 * cg);
        const f32x4 br1 = *(const f32x4*)(b_r + 8 * cg + 4);
#pragma unroll
        for (int i = 0; i < 4; ++i) {
            ro[i][0] = br0.x; ro[i][1] = br0.y; ro[i][2] = br0.z; ro[i][3] = br0.w;
            ro[i][4] = br1.x; ro[i][5] = br1.y; ro[i][6] = br1.z; ro[i][7] = br1.w;
        }
    }
#pragma unroll 2
    for (int kb = 0; kb < 16; ++kb) {
        f32x4 hq[4];
#pragma unroll
        for (int i = 0; i < 4; ++i)
            hq[i] = *(const f32x4*)&cur[(rg + 16 * i) * 68 + 4 * kb];
#pragma unroll
        for (int kk = 0; kk < 4; ++kk) {
            const f32x4 wa = *(const f32x4*)(W_r + (4 * kb + kk) * 128 + 8 * cg);
            const f32x4 wb = *(const f32x4*)(W_r + (4 * kb + kk) * 128 + 8 * cg + 4);
#pragma unroll
            for (int i = 0; i < 4; ++i) {
                ro[i][0] += hq[i][kk] * wa.x; ro[i][1] += hq[i][kk] * wa.y;
                ro[i][2] += hq[i][kk] * wa.z; ro[i][3] += hq[i][kk] * wa.w;
                ro[i][4] += hq[i][kk] * wb.x; ro[i][5] += hq[i][kk] * wb.y;
                ro[i][6] += hq[i][kk] * wb.z; ro[i][7] += hq[i][kk] * wb.w;
            }
        }
    }
#pragma unroll 2
    for (int kb = 0; kb < 16; ++kb) {
        f32x4 nq[4];
#pragma unroll
        for (int i = 0; i < 4; ++i)
            nq[i] = *(const f32x4*)&oth[(rg + 16 * i) * 68 + 4 * kb];
#pragma unroll
        for (int kk = 0; kk < 4; ++kk) {
            const f32x4 wa = *(const f32x4*)(W_r + (64 + 4 * kb + kk) * 128 + 8 * cg);
            const f32x4 wb = *(const f32x4*)(W_r + (64 + 4 * kb + kk) * 128 + 8 * cg + 4);
#pragma unroll
            for (int i = 0; i < 4; ++i) {
                ro[i][0] += nq[i][kk] * wa.x; ro[i][1] += nq[i][kk] * wa.y;
                ro[i][2] += nq[i][kk] * wa.z; ro[i][3] += nq[i][kk] * wa.w;
                ro[i][4] += nq[i][kk] * wb.x; ro[i][5] += nq[i][kk] * wb.y;
                ro[i][6] += nq[i][kk] * wb.z; ro[i][7] += nq[i][kk] * wb.w;
            }
        }
    }
    // relu + node mask + in-thread row sum
    float rs[8];
#pragma unroll
    for (int j = 0; j < 8; ++j) rs[j] = 0.f;
#pragma unroll
    for (int i = 0; i < 4; ++i)
#pragma unroll
        for (int j = 0; j < 8; ++j) rs[j] += updf[i] * fmaxf(ro[i][j], 0.f);

    __syncthreads();   // all readout reads of bufB (nodes) done before overlay 3
    float* red = bufB; // overlay 3: red[16][128]
    *(float4*)&red[rg * 128 + 8 * cg]     = make_float4(rs[0], rs[1], rs[2], rs[3]);
    *(float4*)&red[rg * 128 + 8 * cg + 4] = make_float4(rs[4], rs[5], rs[6], rs[7]);
    __syncthreads();
    if (t < 128) {
        float sum = 0.f;
#pragma unroll
        for (int i = 0; i < 16; ++i) sum += red[i * 128 + t];
        out[(size_t)b * 128 + t] = sum;
    }
}

// ---------------------------------------------------------------------------
extern "C" void kernel_launch(void* const* d_in, const int* in_sizes, int n_in,
                              void* d_out, int out_size, void* d_ws, size_t ws_size,
                              hipStream_t stream)
{
    const int*   adjacency = (const int*)  d_in[0];
    const float* nodes     = (const float*)d_in[1];
    const float* edges     = (const float*)d_in[2];
    const float* W_n       = (const float*)d_in[3];
    const float* W_e       = (const float*)d_in[4];
    const float* b_m       = (const float*)d_in[5];
    const float* W_u       = (const float*)d_in[6];
    const float* b_u       = (const float*)d_in[7];
    const float* W_r       = (const float*)d_in[8];
    const float* b_r       = (const float*)d_in[9];
    float* out = (float*)d_out;
    float* ws  = (float*)d_ws;   // 5184 floats

    prep_kernel<<<81, 64, 0, stream>>>(W_n, W_e, b_m, W_u, b_u, ws);
    mpnn_kernel<<<1024, 256, 0, stream>>>(adjacency, nodes, edges, W_u, W_r, b_r, ws, out);
}